// Round 13
// baseline (245.400 us; speedup 1.0000x reference)
//
#include <hip/hip_runtime.h>
#include <hip/hip_bf16.h>
#include <cstdint>
#include <cstddef>

// LearnableUpsampler: quant -> convT(K=4,s=2) -> quant -> conv7+silu -> quant -> conv7 + res -> LN
// Round 23: R12 (185.1us best: product-8 coverage at 460MB L2 traffic, full fusion) + two
// scheduling-only edits targeting the tap-boundary serialization (next-tap B-loads sit
// after the acc fold in program order -> each of 7 tap boundaries exposes an L2 round-trip):
//  (1) tap loop unroll 1 -> 2: scheduler can hoist tap t+1's independent B-loads above
//      tap t's MFMA burst + fold (cross-tap pipelining, no LDS/barrier cost).
//  (2) s_setprio(1) around the MFMA inner loop (waves are barrier-free + independent
//      post-prologue -> the regime where setprio measured +4-7%).
// Numerics bit-identical to R12. All reductions fixed-order (replay-deterministic).

#define B_ 2
#define T_ 2048
#define L_ 4096
#define C_ 512

static constexpr int NUP = 512 * 512 * 4;
static constexpr int NR  = 512 * 512 * 7;

using v4i  = __attribute__((ext_vector_type(4))) int;

__device__ __forceinline__ void gl16(const void* g, void* l) {
  __builtin_amdgcn_global_load_lds((const __attribute__((address_space(1))) unsigned int*)g,
                                   (__attribute__((address_space(3))) unsigned int*)l,
                                   16, 0, 0);
}

// ---------------- reductions ----------------

__device__ inline float block_reduce_sum_256(float v) {
  #pragma unroll
  for (int off = 32; off > 0; off >>= 1) v += __shfl_down(v, off, 64);
  __shared__ float s[4];
  __syncthreads();
  if ((threadIdx.x & 63) == 0) s[threadIdx.x >> 6] = v;
  __syncthreads();
  return (s[0] + s[1]) + (s[2] + s[3]);
}

// stage 1: fixed-slot partial sums (deterministic: no atomics)
__global__ void abssum3_partial(const float* __restrict__ w0, const float* __restrict__ w1,
                                const float* __restrict__ w2, float* __restrict__ partial) {
  int y = blockIdx.y;
  const float* w = (y == 0) ? w0 : (y == 1) ? w1 : w2;
  int n = (y == 0) ? NUP : NR;
  int idx = blockIdx.x * 256 + threadIdx.x;
  float s = 0.f;
  for (int i = idx; i < n; i += gridDim.x * 256) s += fabsf(w[i]);
  s = block_reduce_sum_256(s);
  if (threadIdx.x == 0) partial[y * 256 + blockIdx.x] = s;
}

// stage 2: fixed-order tree over the 256 partials (deterministic)
__global__ void abssum3_final(const float* __restrict__ partial, float* __restrict__ out) {
  int y = blockIdx.x;
  float v = partial[y * 256 + threadIdx.x];
  v = block_reduce_sum_256(v);
  if (threadIdx.x == 0) out[y] = v;
}

// ---------------- ternarize + repack, one launch; layout [tap][kq32][co512][16] ----------------
__global__ void tern_all_kernel(const float* __restrict__ wu, const float* __restrict__ w1,
                                const float* __restrict__ w2, int8_t* __restrict__ ou,
                                int8_t* __restrict__ o1, int8_t* __restrict__ o2,
                                const float* __restrict__ wsum) {
  int y = blockIdx.y;
  int idx = blockIdx.x * 256 + threadIdx.x;
  if (y == 0) {
    if (idx >= NUP) return;
    float mean = wsum[0] * (1.0f / (float)NUP);
    float scale = 1.0f / fmaxf(mean, 1e-5f);
    float t = rintf(wu[idx] * scale);
    t = fminf(fmaxf(t, -1.f), 1.f);
    int ci = idx >> 11;
    int co = (idx >> 2) & 511;
    int k = idx & 3;
    // ptap order: parity0 {k=3,k=1}, parity1 {k=2,k=0}
    int ptap = (k == 3) ? 0 : (k == 1) ? 1 : (k == 2) ? 2 : 3;
    ou[(((size_t)ptap * 32 + (ci >> 4)) * 512 + co) * 16 + (ci & 15)] = (int8_t)t;
  } else {
    if (idx >= NR) return;
    const float* w = (y == 1) ? w1 : w2;
    int8_t* o = (y == 1) ? o1 : o2;
    float mean = wsum[y] * (1.0f / (float)NR);
    float scale = 1.0f / fmaxf(mean, 1e-5f);
    float t = rintf(w[idx] * scale);
    t = fminf(fmaxf(t, -1.f), 1.f);
    int co = idx / 3584;
    int rem = idx - co * 3584;
    int ci = rem / 7;
    int k = rem - ci * 7;
    o[(((size_t)k * 32 + (ci >> 4)) * 512 + co) * 16 + (ci & 15)] = (int8_t)t;
  }
}

// ---------------- per-token activation quant for x; packed q layout [b][kq32][LinH][16] ----------------
__global__ void act_quant_kernel(const float* __restrict__ x, int8_t* __restrict__ qd,
                                 float* __restrict__ inv, int Lb, int lbsh, int LinH) {
  int tok = blockIdx.x;
  int b = tok >> lbsh;
  int t = tok & (Lb - 1);
  const float* row = x + (size_t)tok * C_;
  int tid = threadIdx.x;
  float v0 = row[tid];
  float v1 = row[tid + 256];
  float m = fmaxf(fabsf(v0), fabsf(v1));
  #pragma unroll
  for (int off = 32; off > 0; off >>= 1) m = fmaxf(m, __shfl_down(m, off, 64));
  __shared__ float s[4];
  __shared__ __align__(16) int8_t sq[512];
  if ((tid & 63) == 0) s[tid >> 6] = m;
  __syncthreads();
  m = fmaxf(fmaxf(s[0], s[1]), fmaxf(s[2], s[3]));
  float scale = 127.0f / fmaxf(m, 1e-5f);
  float q0 = fminf(fmaxf(rintf(v0 * scale), -128.f), 127.f);
  float q1 = fminf(fmaxf(rintf(v1 * scale), -128.f), 127.f);
  sq[tid] = (int8_t)q0;
  sq[tid + 256] = (int8_t)q1;
  __syncthreads();
  if (tid < 32)
    *(v4i*)(qd + ((size_t)(b * 32 + tid) * LinH + 8 + t) * 16) = *(const v4i*)(sq + tid * 16);
  if (tid == 0) inv[(size_t)b * LinH + 8 + t] = 1.0f / scale;
}

// ---------------- fused MFMA conv (16x16x64, 2 M-reps share each B-frag) ----------------
// Block 1024 thr (16 waves). Block tile 32M x 512N (token-complete). Wave w: cols
// [w*32, +32) as 2 col-groups of 16; M via 2 reps (rows 0-15, 16-31). Lane: l15 = col /
// A-row, l4 = k-quarter. Per (tap,kc): 2 A ds_reads + 2 B loads -> 4 MFMA. A staged once.
// Grid 256 = 1 block/CU -> weight L2 traffic 460MB (traffic-optimal).
// EPI: 0 = write h f32 + quant    1 = silu + quant (no f32)    2 = +res + LayerNorm
template<int NTAPS, bool CONVT, int EPI>
__global__ __launch_bounds__(1024, 4)
void conv_fused(const int8_t* __restrict__ qin, const float* __restrict__ invp, int LinH,
                const int8_t* __restrict__ wq, const float* __restrict__ wsum, int widx,
                float wninv, const float* __restrict__ bias,
                float* __restrict__ hout,
                int8_t* __restrict__ qout, float* __restrict__ invout, int LoutH,
                const float* __restrict__ res, const float* __restrict__ g,
                const float* __restrict__ be, float* __restrict__ lnout, int Lout) {
  __shared__ __align__(16) int8_t sA[32 * 38 * 16];      // 19456 B
  __shared__ float sInv[40];
  __shared__ float sRedA[16][32];
  __shared__ float sRedB[16][32];
  __shared__ float sS0[32];
  __shared__ float sS1[32];
  __shared__ __align__(16) int8_t sQ[32][512];           // 16 KB (EPI 0/1 only)

  const int tid = threadIdx.x;
  const int w = tid >> 6, lane = tid & 63;
  const int l15 = lane & 15, l4 = lane >> 4;             // l4 in 0..3 = k-quarter
  const int t0 = blockIdx.x * 32;
  const int b = blockIdx.y;
  int s0 = -3;
  const int8_t* wq_p = wq;
  int parity = 0;
  if (CONVT) {
    parity = blockIdx.z;
    s0 = parity - 1;
    wq_p += (size_t)parity * 2 * 32 * 512 * 16;
  }
  const int8_t* qin_b = qin + (size_t)b * 32 * LinH * 16;
  const float* inv_b = invp + (size_t)b * LinH + 8;

  // ---- prologue: stage A (32 kq x 38 rows = 1216 16B units) + sInv, one barrier
  #pragma unroll
  for (int i = 0; i < 2; ++i) {
    int base = i * 1024 + w * 64;      // wave-uniform
    if (base < 1216) {
      int u = base + lane;
      int kq = u / 38;
      int row = u - kq * 38;
      gl16(qin_b + ((size_t)kq * LinH + (size_t)(t0 + 5 + row)) * 16,
           sA + (size_t)base * 16);
    }
  }
  if (tid < 38) sInv[tid] = inv_b[t0 - 3 + tid];
  __syncthreads();   // drains gl16 (vmcnt) + sInv write; the ONLY main-path barrier

  float fs00[4], fs01[4], fs10[4], fs11[4];
  v4i acc00{}, acc01{}, acc10{}, acc11{};
  #pragma unroll
  for (int r = 0; r < 4; ++r) {
    fs00[r] = 0.f; fs01[r] = 0.f; fs10[r] = 0.f; fs11[r] = 0.f;
    acc00[r] = 0; acc01[r] = 0; acc10[r] = 0; acc11[r] = 0;
  }

  const int c0 = w * 32;
  // per-lane B base: k-quarter l4, col c0+l15 (group 0) / +16 (group 1)
  const int8_t* wb = wq_p + ((size_t)l4 * 512 + (size_t)(c0 + l15)) * 16;
  // per-lane A base in LDS: k-quarter l4 rows
  const int8_t* aB = sA + (size_t)l4 * (38 * 16);

  #pragma unroll 2
  for (int tap = 0; tap < NTAPS; ++tap) {
    const int shift = s0 + tap;
    const int8_t* aP = aB + (size_t)(3 + shift + l15) * 16;
    const int8_t* wt = wb + (size_t)tap * (32 * 512 * 16);
    __builtin_amdgcn_s_setprio(1);
    #pragma unroll
    for (int kc = 0; kc < 8; ++kc) {
      v4i a0 = *(const v4i*)(aP + (size_t)kc * (4 * 38 * 16));          // rows 0..15
      v4i a1 = *(const v4i*)(aP + (size_t)kc * (4 * 38 * 16) + 256);    // rows 16..31
      v4i b0 = *(const v4i*)(wt + (size_t)kc * 32768);                  // cols c0..+15
      v4i b1 = *(const v4i*)(wt + (size_t)kc * 32768 + 256);            // cols +16..+31
      acc00 = __builtin_amdgcn_mfma_i32_16x16x64_i8(a0, b0, acc00, 0, 0, 0);
      acc01 = __builtin_amdgcn_mfma_i32_16x16x64_i8(a0, b1, acc01, 0, 0, 0);
      acc10 = __builtin_amdgcn_mfma_i32_16x16x64_i8(a1, b0, acc10, 0, 0, 0);
      acc11 = __builtin_amdgcn_mfma_i32_16x16x64_i8(a1, b1, acc11, 0, 0, 0);
    }
    __builtin_amdgcn_s_setprio(0);
    // end of tap: fold i32 -> fp32 with per-input-row scale (token m = mrep*16 + l4*4 + r)
    #pragma unroll
    for (int r = 0; r < 4; ++r) {
      float sc0 = sInv[3 + shift + l4 * 4 + r];
      float sc1 = sInv[3 + shift + 16 + l4 * 4 + r];
      fs00[r] = fmaf((float)acc00[r], sc0, fs00[r]);
      fs01[r] = fmaf((float)acc01[r], sc0, fs01[r]);
      fs10[r] = fmaf((float)acc10[r], sc1, fs10[r]);
      fs11[r] = fmaf((float)acc11[r], sc1, fs11[r]);
      acc00[r] = 0; acc01[r] = 0; acc10[r] = 0; acc11[r] = 0;
    }
  }

  // ---- epilogue: bias/dequant, then fused consumer stage
  const float wdq = fmaxf(wsum[widx] * wninv, 1e-5f);
  const float bv0 = bias[c0 + l15];
  const float bv1 = bias[c0 + 16 + l15];
  #pragma unroll
  for (int r = 0; r < 4; ++r) {
    fs00[r] = fs00[r] * wdq + bv0;
    fs01[r] = fs01[r] * wdq + bv1;
    fs10[r] = fs10[r] * wdq + bv0;
    fs11[r] = fs11[r] * wdq + bv1;
  }

  if constexpr (EPI == 0) {
    // write h f32 (out token = 2*(t0+m)+parity)
    #pragma unroll
    for (int mrep = 0; mrep < 2; ++mrep) {
      #pragma unroll
      for (int r = 0; r < 4; ++r) {
        int m = mrep * 16 + l4 * 4 + r;
        size_t base = ((size_t)b * Lout + 2 * (size_t)(t0 + m) + parity) * 512;
        hout[base + c0 + l15]      = (mrep == 0) ? fs00[r] : fs10[r];
        hout[base + c0 + 16 + l15] = (mrep == 0) ? fs01[r] : fs11[r];
      }
    }
  }
  if constexpr (EPI == 1) {
    #pragma unroll
    for (int r = 0; r < 4; ++r) {
      fs00[r] = fs00[r] / (1.0f + expf(-fs00[r]));
      fs01[r] = fs01[r] / (1.0f + expf(-fs01[r]));
      fs10[r] = fs10[r] / (1.0f + expf(-fs10[r]));
      fs11[r] = fs11[r] / (1.0f + expf(-fs11[r]));
    }
  }

  if constexpr (EPI <= 1) {
    // ---- per-token absmax (deterministic: 16-lane shuffle tree + fixed 16-wave fold)
    #pragma unroll
    for (int mrep = 0; mrep < 2; ++mrep) {
      #pragma unroll
      for (int r = 0; r < 4; ++r) {
        int m = mrep * 16 + l4 * 4 + r;
        float mv = (mrep == 0) ? fmaxf(fabsf(fs00[r]), fabsf(fs01[r]))
                               : fmaxf(fabsf(fs10[r]), fabsf(fs11[r]));
        #pragma unroll
        for (int off = 8; off > 0; off >>= 1) mv = fmaxf(mv, __shfl_xor(mv, off, 64));
        if (l15 == 0) sRedA[w][m] = mv;
      }
    }
    __syncthreads();
    if (tid < 32) {
      float mval = sRedA[0][tid];
      #pragma unroll
      for (int ww = 1; ww < 16; ++ww) mval = fmaxf(mval, sRedA[ww][tid]);
      float mm = fmaxf(mval, 1e-5f);
      sS0[tid] = 127.0f / mm;
      int tok = CONVT ? (2 * (t0 + tid) + parity) : (t0 + tid);
      invout[(size_t)b * LoutH + 8 + tok] = mm * (1.0f / 127.0f);
    }
    __syncthreads();
    #pragma unroll
    for (int mrep = 0; mrep < 2; ++mrep) {
      #pragma unroll
      for (int r = 0; r < 4; ++r) {
        int m = mrep * 16 + l4 * 4 + r;
        float sc = sS0[m];
        float v0 = (mrep == 0) ? fs00[r] : fs10[r];
        float v1 = (mrep == 0) ? fs01[r] : fs11[r];
        float q0 = fminf(fmaxf(rintf(v0 * sc), -128.f), 127.f);
        float q1 = fminf(fmaxf(rintf(v1 * sc), -128.f), 127.f);
        sQ[m][c0 + l15] = (int8_t)q0;
        sQ[m][c0 + 16 + l15] = (int8_t)q1;
      }
    }
    __syncthreads();
    {
      int row = tid >> 5, unit = tid & 31;   // 32 rows x 32 units = 1024
      int tok = CONVT ? (2 * (t0 + row) + parity) : (t0 + row);
      *(v4i*)(qout + (((size_t)b * 32 + unit) * LoutH + 8 + tok) * 16) =
          *(const v4i*)(&sQ[row][unit * 16]);
    }
  } else {
    // ---- EPI 2: residual + deterministic two-pass LayerNorm
    #pragma unroll
    for (int mrep = 0; mrep < 2; ++mrep) {
      #pragma unroll
      for (int r = 0; r < 4; ++r) {
        int m = mrep * 16 + l4 * 4 + r;
        size_t base = ((size_t)b * Lout + (size_t)(t0 + m)) * 512;
        if (mrep == 0) { fs00[r] += res[base + c0 + l15]; fs01[r] += res[base + c0 + 16 + l15]; }
        else           { fs10[r] += res[base + c0 + l15]; fs11[r] += res[base + c0 + 16 + l15]; }
      }
    }
    // pass 1: mean
    #pragma unroll
    for (int mrep = 0; mrep < 2; ++mrep) {
      #pragma unroll
      for (int r = 0; r < 4; ++r) {
        int m = mrep * 16 + l4 * 4 + r;
        float s = (mrep == 0) ? (fs00[r] + fs01[r]) : (fs10[r] + fs11[r]);
        #pragma unroll
        for (int off = 8; off > 0; off >>= 1) s += __shfl_xor(s, off, 64);
        if (l15 == 0) sRedA[w][m] = s;
      }
    }
    __syncthreads();
    if (tid < 32) {
      float s = sRedA[0][tid];
      #pragma unroll
      for (int ww = 1; ww < 16; ++ww) s += sRedA[ww][tid];
      sS0[tid] = s * (1.0f / 512.0f);
    }
    __syncthreads();
    // pass 2: variance around mean
    #pragma unroll
    for (int mrep = 0; mrep < 2; ++mrep) {
      #pragma unroll
      for (int r = 0; r < 4; ++r) {
        int m = mrep * 16 + l4 * 4 + r;
        float mu = sS0[m];
        float d0 = ((mrep == 0) ? fs00[r] : fs10[r]) - mu;
        float d1 = ((mrep == 0) ? fs01[r] : fs11[r]) - mu;
        float ss = d0 * d0 + d1 * d1;
        #pragma unroll
        for (int off = 8; off > 0; off >>= 1) ss += __shfl_xor(ss, off, 64);
        if (l15 == 0) sRedB[w][m] = ss;
      }
    }
    __syncthreads();
    if (tid < 32) {
      float ssum = sRedB[0][tid];
      #pragma unroll
      for (int ww = 1; ww < 16; ++ww) ssum += sRedB[ww][tid];
      float var = ssum * (1.0f / 512.0f);
      sS1[tid] = 1.0f / sqrtf(var + 1e-5f);
    }
    __syncthreads();
    const float g0 = g[c0 + l15], g1 = g[c0 + 16 + l15];
    const float e0 = be[c0 + l15], e1 = be[c0 + 16 + l15];
    #pragma unroll
    for (int mrep = 0; mrep < 2; ++mrep) {
      #pragma unroll
      for (int r = 0; r < 4; ++r) {
        int m = mrep * 16 + l4 * 4 + r;
        float mu = sS0[m], rs = sS1[m];
        size_t base = ((size_t)b * Lout + (size_t)(t0 + m)) * 512;
        float v0 = (mrep == 0) ? fs00[r] : fs10[r];
        float v1 = (mrep == 0) ? fs01[r] : fs11[r];
        lnout[base + c0 + l15]      = (v0 - mu) * rs * g0 + e0;
        lnout[base + c0 + 16 + l15] = (v1 - mu) * rs * g1 + e1;
      }
    }
  }
}

// ---------------- launch ----------------

extern "C" void kernel_launch(void* const* d_in, const int* in_sizes, int n_in,
                              void* d_out, int out_size, void* d_ws, size_t ws_size,
                              hipStream_t stream) {
  const float* x    = (const float*)d_in[0];
  const float* w_up = (const float*)d_in[1];
  const float* b_up = (const float*)d_in[2];
  const float* w_r1 = (const float*)d_in[3];
  const float* b_r1 = (const float*)d_in[4];
  const float* w_r2 = (const float*)d_in[5];
  const float* b_r2 = (const float*)d_in[6];
  const float* ln_w = (const float*)d_in[7];
  const float* ln_b = (const float*)d_in[8];
  float* out = (float*)d_out;

  const int LXH = T_ + 16;   // 2064 rows per batch (halo 8 each side)
  const int LHH = L_ + 16;   // 4112

  char* ws = (char*)d_ws;
  size_t off = 0;
  auto alloc = [&](size_t sz) { size_t p = off; off += (sz + 255) & ~(size_t)255; return p; };
  // zero region: wsum + q buffers + inv buffers (halo rows/scales must be 0)
  float*  wsum  = (float*) (ws + alloc(256));
  int8_t* qx    = (int8_t*)(ws + alloc((size_t)B_ * 32 * LXH * 16));   // 2.1 MB
  int8_t* qh    = (int8_t*)(ws + alloc((size_t)B_ * 32 * LHH * 16));   // 4.2 MB
  int8_t* qh2   = (int8_t*)(ws + alloc((size_t)B_ * 32 * LHH * 16));   // 4.2 MB
  float*  invx  = (float*) (ws + alloc((size_t)B_ * LXH * 4));
  float*  invh  = (float*) (ws + alloc((size_t)B_ * LHH * 4));
  float*  invh2 = (float*) (ws + alloc((size_t)B_ * LHH * 4));
  size_t zero_bytes = off;
  float*  partial = (float*)(ws + alloc(3 * 256 * 4));                 // det. reduction slots
  int8_t* wqup = (int8_t*)(ws + alloc((size_t)4 * 32 * 512 * 16));     // 1 MB
  int8_t* wq1  = (int8_t*)(ws + alloc((size_t)7 * 32 * 512 * 16));     // 1.8 MB
  int8_t* wq2  = (int8_t*)(ws + alloc((size_t)7 * 32 * 512 * 16));     // 1.8 MB
  float*  h    = (float*) (ws + alloc((size_t)B_ * L_ * C_ * 4));      // 16.8 MB

  hipMemsetAsync(ws, 0, zero_bytes, stream);  // wsum + q/inv halos

  abssum3_partial<<<dim3(256, 3), 256, 0, stream>>>(w_up, w_r1, w_r2, partial);
  abssum3_final<<<3, 256, 0, stream>>>(partial, wsum);
  tern_all_kernel<<<dim3(NR / 256, 3), 256, 0, stream>>>(w_up, w_r1, w_r2,
                                                         wqup, wq1, wq2, wsum);

  act_quant_kernel<<<B_ * T_, 256, 0, stream>>>(x, qx, invx, T_, 11, LXH);

  // convT + fused quant: grid (64 mtiles, B, parity) = 256 blocks = 1/CU
  conv_fused<2, true, 0><<<dim3(T_ / 32, B_, 2), 1024, 0, stream>>>(
      qx, invx, LXH, wqup, wsum, 0, 1.0f / (float)NUP, b_up,
      h, qh, invh, LHH, nullptr, nullptr, nullptr, nullptr, L_);

  // conv7#1 + silu + fused quant (no f32 r buffer): grid (128, B) = 256 blocks = 1/CU
  conv_fused<7, false, 1><<<dim3(L_ / 32, B_, 1), 1024, 0, stream>>>(
      qh, invh, LHH, wq1, wsum, 1, 1.0f / (float)NR, b_r1,
      nullptr, qh2, invh2, LHH, nullptr, nullptr, nullptr, nullptr, L_);

  // conv7#2 + residual + fused LayerNorm -> out: grid (128, B) = 256 blocks = 1/CU
  conv_fused<7, false, 2><<<dim3(L_ / 32, B_, 1), 1024, 0, stream>>>(
      qh2, invh2, LHH, wq2, wsum, 2, 1.0f / (float)NR, b_r2,
      nullptr, nullptr, nullptr, 0, h, ln_w, ln_b, out, L_);
}

// Round 14
// 184.724 us; speedup vs baseline: 1.3285x; 1.3285x over previous
//
#include <hip/hip_runtime.h>
#include <hip/hip_bf16.h>
#include <cstdint>
#include <cstddef>

// LearnableUpsampler: quant -> convT(K=4,s=2) -> quant -> conv7+silu -> quant -> conv7 + res -> LN
// Round 24: REVERT to R12/R22 exactly (185.1us measured best). R13's unroll-2 + setprio
// spilled (FETCH 19->124MB, WRITE 16->113MB = scratch traffic) — third spill death of
// cross-tap register pipelining; lever retired. This round is a byte-identical reproduction
// of the best kernel: product-8 coverage (mfma_i32_16x16x64, 2 M-reps share each B-frag),
// 460MB traffic-optimal grid (256 token-complete 32-token blocks = 1/CU), full epilogue
// fusion (convT->quant, conv7#1->silu+quant no-f32, conv7#2->res+LN), all reductions
// fixed-order (replay-deterministic).

#define B_ 2
#define T_ 2048
#define L_ 4096
#define C_ 512

static constexpr int NUP = 512 * 512 * 4;
static constexpr int NR  = 512 * 512 * 7;

using v4i  = __attribute__((ext_vector_type(4))) int;

__device__ __forceinline__ void gl16(const void* g, void* l) {
  __builtin_amdgcn_global_load_lds((const __attribute__((address_space(1))) unsigned int*)g,
                                   (__attribute__((address_space(3))) unsigned int*)l,
                                   16, 0, 0);
}

// ---------------- reductions ----------------

__device__ inline float block_reduce_sum_256(float v) {
  #pragma unroll
  for (int off = 32; off > 0; off >>= 1) v += __shfl_down(v, off, 64);
  __shared__ float s[4];
  __syncthreads();
  if ((threadIdx.x & 63) == 0) s[threadIdx.x >> 6] = v;
  __syncthreads();
  return (s[0] + s[1]) + (s[2] + s[3]);
}

// stage 1: fixed-slot partial sums (deterministic: no atomics)
__global__ void abssum3_partial(const float* __restrict__ w0, const float* __restrict__ w1,
                                const float* __restrict__ w2, float* __restrict__ partial) {
  int y = blockIdx.y;
  const float* w = (y == 0) ? w0 : (y == 1) ? w1 : w2;
  int n = (y == 0) ? NUP : NR;
  int idx = blockIdx.x * 256 + threadIdx.x;
  float s = 0.f;
  for (int i = idx; i < n; i += gridDim.x * 256) s += fabsf(w[i]);
  s = block_reduce_sum_256(s);
  if (threadIdx.x == 0) partial[y * 256 + blockIdx.x] = s;
}

// stage 2: fixed-order tree over the 256 partials (deterministic)
__global__ void abssum3_final(const float* __restrict__ partial, float* __restrict__ out) {
  int y = blockIdx.x;
  float v = partial[y * 256 + threadIdx.x];
  v = block_reduce_sum_256(v);
  if (threadIdx.x == 0) out[y] = v;
}

// ---------------- ternarize + repack, one launch; layout [tap][kq32][co512][16] ----------------
__global__ void tern_all_kernel(const float* __restrict__ wu, const float* __restrict__ w1,
                                const float* __restrict__ w2, int8_t* __restrict__ ou,
                                int8_t* __restrict__ o1, int8_t* __restrict__ o2,
                                const float* __restrict__ wsum) {
  int y = blockIdx.y;
  int idx = blockIdx.x * 256 + threadIdx.x;
  if (y == 0) {
    if (idx >= NUP) return;
    float mean = wsum[0] * (1.0f / (float)NUP);
    float scale = 1.0f / fmaxf(mean, 1e-5f);
    float t = rintf(wu[idx] * scale);
    t = fminf(fmaxf(t, -1.f), 1.f);
    int ci = idx >> 11;
    int co = (idx >> 2) & 511;
    int k = idx & 3;
    // ptap order: parity0 {k=3,k=1}, parity1 {k=2,k=0}
    int ptap = (k == 3) ? 0 : (k == 1) ? 1 : (k == 2) ? 2 : 3;
    ou[(((size_t)ptap * 32 + (ci >> 4)) * 512 + co) * 16 + (ci & 15)] = (int8_t)t;
  } else {
    if (idx >= NR) return;
    const float* w = (y == 1) ? w1 : w2;
    int8_t* o = (y == 1) ? o1 : o2;
    float mean = wsum[y] * (1.0f / (float)NR);
    float scale = 1.0f / fmaxf(mean, 1e-5f);
    float t = rintf(w[idx] * scale);
    t = fminf(fmaxf(t, -1.f), 1.f);
    int co = idx / 3584;
    int rem = idx - co * 3584;
    int ci = rem / 7;
    int k = rem - ci * 7;
    o[(((size_t)k * 32 + (ci >> 4)) * 512 + co) * 16 + (ci & 15)] = (int8_t)t;
  }
}

// ---------------- per-token activation quant for x; packed q layout [b][kq32][LinH][16] ----------------
__global__ void act_quant_kernel(const float* __restrict__ x, int8_t* __restrict__ qd,
                                 float* __restrict__ inv, int Lb, int lbsh, int LinH) {
  int tok = blockIdx.x;
  int b = tok >> lbsh;
  int t = tok & (Lb - 1);
  const float* row = x + (size_t)tok * C_;
  int tid = threadIdx.x;
  float v0 = row[tid];
  float v1 = row[tid + 256];
  float m = fmaxf(fabsf(v0), fabsf(v1));
  #pragma unroll
  for (int off = 32; off > 0; off >>= 1) m = fmaxf(m, __shfl_down(m, off, 64));
  __shared__ float s[4];
  __shared__ __align__(16) int8_t sq[512];
  if ((tid & 63) == 0) s[tid >> 6] = m;
  __syncthreads();
  m = fmaxf(fmaxf(s[0], s[1]), fmaxf(s[2], s[3]));
  float scale = 127.0f / fmaxf(m, 1e-5f);
  float q0 = fminf(fmaxf(rintf(v0 * scale), -128.f), 127.f);
  float q1 = fminf(fmaxf(rintf(v1 * scale), -128.f), 127.f);
  sq[tid] = (int8_t)q0;
  sq[tid + 256] = (int8_t)q1;
  __syncthreads();
  if (tid < 32)
    *(v4i*)(qd + ((size_t)(b * 32 + tid) * LinH + 8 + t) * 16) = *(const v4i*)(sq + tid * 16);
  if (tid == 0) inv[(size_t)b * LinH + 8 + t] = 1.0f / scale;
}

// ---------------- fused MFMA conv (16x16x64, 2 M-reps share each B-frag) ----------------
// Block 1024 thr (16 waves). Block tile 32M x 512N (token-complete). Wave w: cols
// [w*32, +32) as 2 col-groups of 16; M via 2 reps (rows 0-15, 16-31). Lane: l15 = col /
// A-row, l4 = k-quarter. Per (tap,kc): 2 A ds_reads + 2 B loads -> 4 MFMA (each B used
// 2x -> latency coverage 2 MFMA/load at 4 waves/SIMD). A staged once (38 rows, 19.5KB).
// Grid 256 = 1 block/CU -> weight L2 traffic 460MB (the R9 optimum, half of R11's).
// EPI: 0 = write h f32 + quant    1 = silu + quant (no f32)    2 = +res + LayerNorm
template<int NTAPS, bool CONVT, int EPI>
__global__ __launch_bounds__(1024, 4)
void conv_fused(const int8_t* __restrict__ qin, const float* __restrict__ invp, int LinH,
                const int8_t* __restrict__ wq, const float* __restrict__ wsum, int widx,
                float wninv, const float* __restrict__ bias,
                float* __restrict__ hout,
                int8_t* __restrict__ qout, float* __restrict__ invout, int LoutH,
                const float* __restrict__ res, const float* __restrict__ g,
                const float* __restrict__ be, float* __restrict__ lnout, int Lout) {
  __shared__ __align__(16) int8_t sA[32 * 38 * 16];      // 19456 B
  __shared__ float sInv[40];
  __shared__ float sRedA[16][32];
  __shared__ float sRedB[16][32];
  __shared__ float sS0[32];
  __shared__ float sS1[32];
  __shared__ __align__(16) int8_t sQ[32][512];           // 16 KB (EPI 0/1 only)

  const int tid = threadIdx.x;
  const int w = tid >> 6, lane = tid & 63;
  const int l15 = lane & 15, l4 = lane >> 4;             // l4 in 0..3 = k-quarter
  const int t0 = blockIdx.x * 32;
  const int b = blockIdx.y;
  int s0 = -3;
  const int8_t* wq_p = wq;
  int parity = 0;
  if (CONVT) {
    parity = blockIdx.z;
    s0 = parity - 1;
    wq_p += (size_t)parity * 2 * 32 * 512 * 16;
  }
  const int8_t* qin_b = qin + (size_t)b * 32 * LinH * 16;
  const float* inv_b = invp + (size_t)b * LinH + 8;

  // ---- prologue: stage A (32 kq x 38 rows = 1216 16B units) + sInv, one barrier
  #pragma unroll
  for (int i = 0; i < 2; ++i) {
    int base = i * 1024 + w * 64;      // wave-uniform
    if (base < 1216) {
      int u = base + lane;
      int kq = u / 38;
      int row = u - kq * 38;
      gl16(qin_b + ((size_t)kq * LinH + (size_t)(t0 + 5 + row)) * 16,
           sA + (size_t)base * 16);
    }
  }
  if (tid < 38) sInv[tid] = inv_b[t0 - 3 + tid];
  __syncthreads();   // drains gl16 (vmcnt) + sInv write; the ONLY main-path barrier

  float fs00[4], fs01[4], fs10[4], fs11[4];
  v4i acc00{}, acc01{}, acc10{}, acc11{};
  #pragma unroll
  for (int r = 0; r < 4; ++r) {
    fs00[r] = 0.f; fs01[r] = 0.f; fs10[r] = 0.f; fs11[r] = 0.f;
    acc00[r] = 0; acc01[r] = 0; acc10[r] = 0; acc11[r] = 0;
  }

  const int c0 = w * 32;
  // per-lane B base: k-quarter l4, col c0+l15 (group 0) / +16 (group 1)
  const int8_t* wb = wq_p + ((size_t)l4 * 512 + (size_t)(c0 + l15)) * 16;
  // per-lane A base in LDS: k-quarter l4 rows
  const int8_t* aB = sA + (size_t)l4 * (38 * 16);

  #pragma unroll 1
  for (int tap = 0; tap < NTAPS; ++tap) {
    const int shift = s0 + tap;
    const int8_t* aP = aB + (size_t)(3 + shift + l15) * 16;
    const int8_t* wt = wb + (size_t)tap * (32 * 512 * 16);
    #pragma unroll
    for (int kc = 0; kc < 8; ++kc) {
      v4i a0 = *(const v4i*)(aP + (size_t)kc * (4 * 38 * 16));          // rows 0..15
      v4i a1 = *(const v4i*)(aP + (size_t)kc * (4 * 38 * 16) + 256);    // rows 16..31
      v4i b0 = *(const v4i*)(wt + (size_t)kc * 32768);                  // cols c0..+15
      v4i b1 = *(const v4i*)(wt + (size_t)kc * 32768 + 256);            // cols +16..+31
      acc00 = __builtin_amdgcn_mfma_i32_16x16x64_i8(a0, b0, acc00, 0, 0, 0);
      acc01 = __builtin_amdgcn_mfma_i32_16x16x64_i8(a0, b1, acc01, 0, 0, 0);
      acc10 = __builtin_amdgcn_mfma_i32_16x16x64_i8(a1, b0, acc10, 0, 0, 0);
      acc11 = __builtin_amdgcn_mfma_i32_16x16x64_i8(a1, b1, acc11, 0, 0, 0);
    }
    // end of tap: fold i32 -> fp32 with per-input-row scale (token m = mrep*16 + l4*4 + r)
    #pragma unroll
    for (int r = 0; r < 4; ++r) {
      float sc0 = sInv[3 + shift + l4 * 4 + r];
      float sc1 = sInv[3 + shift + 16 + l4 * 4 + r];
      fs00[r] = fmaf((float)acc00[r], sc0, fs00[r]);
      fs01[r] = fmaf((float)acc01[r], sc0, fs01[r]);
      fs10[r] = fmaf((float)acc10[r], sc1, fs10[r]);
      fs11[r] = fmaf((float)acc11[r], sc1, fs11[r]);
      acc00[r] = 0; acc01[r] = 0; acc10[r] = 0; acc11[r] = 0;
    }
  }

  // ---- epilogue: bias/dequant, then fused consumer stage
  const float wdq = fmaxf(wsum[widx] * wninv, 1e-5f);
  const float bv0 = bias[c0 + l15];
  const float bv1 = bias[c0 + 16 + l15];
  #pragma unroll
  for (int r = 0; r < 4; ++r) {
    fs00[r] = fs00[r] * wdq + bv0;
    fs01[r] = fs01[r] * wdq + bv1;
    fs10[r] = fs10[r] * wdq + bv0;
    fs11[r] = fs11[r] * wdq + bv1;
  }

  if constexpr (EPI == 0) {
    // write h f32 (out token = 2*(t0+m)+parity)
    #pragma unroll
    for (int mrep = 0; mrep < 2; ++mrep) {
      #pragma unroll
      for (int r = 0; r < 4; ++r) {
        int m = mrep * 16 + l4 * 4 + r;
        size_t base = ((size_t)b * Lout + 2 * (size_t)(t0 + m) + parity) * 512;
        hout[base + c0 + l15]      = (mrep == 0) ? fs00[r] : fs10[r];
        hout[base + c0 + 16 + l15] = (mrep == 0) ? fs01[r] : fs11[r];
      }
    }
  }
  if constexpr (EPI == 1) {
    #pragma unroll
    for (int r = 0; r < 4; ++r) {
      fs00[r] = fs00[r] / (1.0f + expf(-fs00[r]));
      fs01[r] = fs01[r] / (1.0f + expf(-fs01[r]));
      fs10[r] = fs10[r] / (1.0f + expf(-fs10[r]));
      fs11[r] = fs11[r] / (1.0f + expf(-fs11[r]));
    }
  }

  if constexpr (EPI <= 1) {
    // ---- per-token absmax (deterministic: 16-lane shuffle tree + fixed 16-wave fold)
    #pragma unroll
    for (int mrep = 0; mrep < 2; ++mrep) {
      #pragma unroll
      for (int r = 0; r < 4; ++r) {
        int m = mrep * 16 + l4 * 4 + r;
        float mv = (mrep == 0) ? fmaxf(fabsf(fs00[r]), fabsf(fs01[r]))
                               : fmaxf(fabsf(fs10[r]), fabsf(fs11[r]));
        #pragma unroll
        for (int off = 8; off > 0; off >>= 1) mv = fmaxf(mv, __shfl_xor(mv, off, 64));
        if (l15 == 0) sRedA[w][m] = mv;
      }
    }
    __syncthreads();
    if (tid < 32) {
      float mval = sRedA[0][tid];
      #pragma unroll
      for (int ww = 1; ww < 16; ++ww) mval = fmaxf(mval, sRedA[ww][tid]);
      float mm = fmaxf(mval, 1e-5f);
      sS0[tid] = 127.0f / mm;
      int tok = CONVT ? (2 * (t0 + tid) + parity) : (t0 + tid);
      invout[(size_t)b * LoutH + 8 + tok] = mm * (1.0f / 127.0f);
    }
    __syncthreads();
    #pragma unroll
    for (int mrep = 0; mrep < 2; ++mrep) {
      #pragma unroll
      for (int r = 0; r < 4; ++r) {
        int m = mrep * 16 + l4 * 4 + r;
        float sc = sS0[m];
        float v0 = (mrep == 0) ? fs00[r] : fs10[r];
        float v1 = (mrep == 0) ? fs01[r] : fs11[r];
        float q0 = fminf(fmaxf(rintf(v0 * sc), -128.f), 127.f);
        float q1 = fminf(fmaxf(rintf(v1 * sc), -128.f), 127.f);
        sQ[m][c0 + l15] = (int8_t)q0;
        sQ[m][c0 + 16 + l15] = (int8_t)q1;
      }
    }
    __syncthreads();
    {
      int row = tid >> 5, unit = tid & 31;   // 32 rows x 32 units = 1024
      int tok = CONVT ? (2 * (t0 + row) + parity) : (t0 + row);
      *(v4i*)(qout + (((size_t)b * 32 + unit) * LoutH + 8 + tok) * 16) =
          *(const v4i*)(&sQ[row][unit * 16]);
    }
  } else {
    // ---- EPI 2: residual + deterministic two-pass LayerNorm
    #pragma unroll
    for (int mrep = 0; mrep < 2; ++mrep) {
      #pragma unroll
      for (int r = 0; r < 4; ++r) {
        int m = mrep * 16 + l4 * 4 + r;
        size_t base = ((size_t)b * Lout + (size_t)(t0 + m)) * 512;
        if (mrep == 0) { fs00[r] += res[base + c0 + l15]; fs01[r] += res[base + c0 + 16 + l15]; }
        else           { fs10[r] += res[base + c0 + l15]; fs11[r] += res[base + c0 + 16 + l15]; }
      }
    }
    // pass 1: mean
    #pragma unroll
    for (int mrep = 0; mrep < 2; ++mrep) {
      #pragma unroll
      for (int r = 0; r < 4; ++r) {
        int m = mrep * 16 + l4 * 4 + r;
        float s = (mrep == 0) ? (fs00[r] + fs01[r]) : (fs10[r] + fs11[r]);
        #pragma unroll
        for (int off = 8; off > 0; off >>= 1) s += __shfl_xor(s, off, 64);
        if (l15 == 0) sRedA[w][m] = s;
      }
    }
    __syncthreads();
    if (tid < 32) {
      float s = sRedA[0][tid];
      #pragma unroll
      for (int ww = 1; ww < 16; ++ww) s += sRedA[ww][tid];
      sS0[tid] = s * (1.0f / 512.0f);
    }
    __syncthreads();
    // pass 2: variance around mean
    #pragma unroll
    for (int mrep = 0; mrep < 2; ++mrep) {
      #pragma unroll
      for (int r = 0; r < 4; ++r) {
        int m = mrep * 16 + l4 * 4 + r;
        float mu = sS0[m];
        float d0 = ((mrep == 0) ? fs00[r] : fs10[r]) - mu;
        float d1 = ((mrep == 0) ? fs01[r] : fs11[r]) - mu;
        float ss = d0 * d0 + d1 * d1;
        #pragma unroll
        for (int off = 8; off > 0; off >>= 1) ss += __shfl_xor(ss, off, 64);
        if (l15 == 0) sRedB[w][m] = ss;
      }
    }
    __syncthreads();
    if (tid < 32) {
      float ssum = sRedB[0][tid];
      #pragma unroll
      for (int ww = 1; ww < 16; ++ww) ssum += sRedB[ww][tid];
      float var = ssum * (1.0f / 512.0f);
      sS1[tid] = 1.0f / sqrtf(var + 1e-5f);
    }
    __syncthreads();
    const float g0 = g[c0 + l15], g1 = g[c0 + 16 + l15];
    const float e0 = be[c0 + l15], e1 = be[c0 + 16 + l15];
    #pragma unroll
    for (int mrep = 0; mrep < 2; ++mrep) {
      #pragma unroll
      for (int r = 0; r < 4; ++r) {
        int m = mrep * 16 + l4 * 4 + r;
        float mu = sS0[m], rs = sS1[m];
        size_t base = ((size_t)b * Lout + (size_t)(t0 + m)) * 512;
        float v0 = (mrep == 0) ? fs00[r] : fs10[r];
        float v1 = (mrep == 0) ? fs01[r] : fs11[r];
        lnout[base + c0 + l15]      = (v0 - mu) * rs * g0 + e0;
        lnout[base + c0 + 16 + l15] = (v1 - mu) * rs * g1 + e1;
      }
    }
  }
}

// ---------------- launch ----------------

extern "C" void kernel_launch(void* const* d_in, const int* in_sizes, int n_in,
                              void* d_out, int out_size, void* d_ws, size_t ws_size,
                              hipStream_t stream) {
  const float* x    = (const float*)d_in[0];
  const float* w_up = (const float*)d_in[1];
  const float* b_up = (const float*)d_in[2];
  const float* w_r1 = (const float*)d_in[3];
  const float* b_r1 = (const float*)d_in[4];
  const float* w_r2 = (const float*)d_in[5];
  const float* b_r2 = (const float*)d_in[6];
  const float* ln_w = (const float*)d_in[7];
  const float* ln_b = (const float*)d_in[8];
  float* out = (float*)d_out;

  const int LXH = T_ + 16;   // 2064 rows per batch (halo 8 each side)
  const int LHH = L_ + 16;   // 4112

  char* ws = (char*)d_ws;
  size_t off = 0;
  auto alloc = [&](size_t sz) { size_t p = off; off += (sz + 255) & ~(size_t)255; return p; };
  // zero region: wsum + q buffers + inv buffers (halo rows/scales must be 0)
  float*  wsum  = (float*) (ws + alloc(256));
  int8_t* qx    = (int8_t*)(ws + alloc((size_t)B_ * 32 * LXH * 16));   // 2.1 MB
  int8_t* qh    = (int8_t*)(ws + alloc((size_t)B_ * 32 * LHH * 16));   // 4.2 MB
  int8_t* qh2   = (int8_t*)(ws + alloc((size_t)B_ * 32 * LHH * 16));   // 4.2 MB
  float*  invx  = (float*) (ws + alloc((size_t)B_ * LXH * 4));
  float*  invh  = (float*) (ws + alloc((size_t)B_ * LHH * 4));
  float*  invh2 = (float*) (ws + alloc((size_t)B_ * LHH * 4));
  size_t zero_bytes = off;
  float*  partial = (float*)(ws + alloc(3 * 256 * 4));                 // det. reduction slots
  int8_t* wqup = (int8_t*)(ws + alloc((size_t)4 * 32 * 512 * 16));     // 1 MB
  int8_t* wq1  = (int8_t*)(ws + alloc((size_t)7 * 32 * 512 * 16));     // 1.8 MB
  int8_t* wq2  = (int8_t*)(ws + alloc((size_t)7 * 32 * 512 * 16));     // 1.8 MB
  float*  h    = (float*) (ws + alloc((size_t)B_ * L_ * C_ * 4));      // 16.8 MB

  hipMemsetAsync(ws, 0, zero_bytes, stream);  // wsum + q/inv halos

  abssum3_partial<<<dim3(256, 3), 256, 0, stream>>>(w_up, w_r1, w_r2, partial);
  abssum3_final<<<3, 256, 0, stream>>>(partial, wsum);
  tern_all_kernel<<<dim3(NR / 256, 3), 256, 0, stream>>>(w_up, w_r1, w_r2,
                                                         wqup, wq1, wq2, wsum);

  act_quant_kernel<<<B_ * T_, 256, 0, stream>>>(x, qx, invx, T_, 11, LXH);

  // convT + fused quant: grid (64 mtiles, B, parity) = 256 blocks = 1/CU
  conv_fused<2, true, 0><<<dim3(T_ / 32, B_, 2), 1024, 0, stream>>>(
      qx, invx, LXH, wqup, wsum, 0, 1.0f / (float)NUP, b_up,
      h, qh, invh, LHH, nullptr, nullptr, nullptr, nullptr, L_);

  // conv7#1 + silu + fused quant (no f32 r buffer): grid (128, B) = 256 blocks = 1/CU
  conv_fused<7, false, 1><<<dim3(L_ / 32, B_, 1), 1024, 0, stream>>>(
      qh, invh, LHH, wq1, wsum, 1, 1.0f / (float)NR, b_r1,
      nullptr, qh2, invh2, LHH, nullptr, nullptr, nullptr, nullptr, L_);

  // conv7#2 + residual + fused LayerNorm -> out: grid (128, B) = 256 blocks = 1/CU
  conv_fused<7, false, 2><<<dim3(L_ / 32, B_, 1), 1024, 0, stream>>>(
      qh2, invh2, LHH, wq2, wsum, 2, 1.0f / (float)NR, b_r2,
      nullptr, nullptr, nullptr, 0, h, ln_w, ln_b, out, L_);
}